// Round 2
// baseline (758.075 us; speedup 1.0000x reference)
//
#include <hip/hip_runtime.h>
#include <hip/hip_bf16.h>

// Problem constants (reference: R=8, N=4096, IN_F=OUT_F=64)
#define RR 8
#define NN 4096
#define FF 64

typedef float f32x4 __attribute__((ext_vector_type(4)));
typedef short bf16x8 __attribute__((ext_vector_type(8)));

__device__ __forceinline__ short f2b(float f) {
  __hip_bfloat16 h = __float2bfloat16(f);
  return __builtin_bit_cast(short, h);
}

__device__ __forceinline__ bf16x8 cvt8(f32x4 lo, f32x4 hi) {
  bf16x8 r;
  r[0] = f2b(lo[0]); r[1] = f2b(lo[1]); r[2] = f2b(lo[2]); r[3] = f2b(lo[3]);
  r[4] = f2b(hi[0]); r[5] = f2b(hi[1]); r[6] = f2b(hi[2]); r[7] = f2b(hi[3]);
  return r;
}

// ---------------------------------------------------------------------------
// Kernel 0: zero the output (harness poisons d_out with 0xAA before every
// timed launch; main kernel accumulates with atomics).
__global__ __launch_bounds__(256) void zero_out(float4* __restrict__ out) {
  out[blockIdx.x * 256 + threadIdx.x] = make_float4(0.f, 0.f, 0.f, 0.f);
}

// ---------------------------------------------------------------------------
// Kernel 1: Zt[r][o][m] = sum_i W[r][o][i] * x[m][i], stored bf16 in d_ws.
// Layout: Zt[r*64*4096 + o*4096 + m]. MFMA: A = W[r] (o x i), B = x^T (i x m).
__global__ __launch_bounds__(256) void compute_zt(const float* __restrict__ x,
                                                  const float* __restrict__ w,
                                                  short* __restrict__ zt) {
  const int tid   = threadIdx.x;
  const int lane  = tid & 63;
  const int wv    = tid >> 6;
  const int row16 = lane & 15;
  const int quad  = lane >> 4;
  const int r     = blockIdx.y;
  const int m0    = blockIdx.x * 64 + wv * 16;

  bf16x8 bfr[2];
#pragma unroll
  for (int s = 0; s < 2; ++s) {
    const float* p = x + (size_t)(m0 + row16) * FF + s * 32 + quad * 8;
    bfr[s] = cvt8(*(const f32x4*)p, *(const f32x4*)(p + 4));
  }

  f32x4 acc[4] = {{0.f,0.f,0.f,0.f},{0.f,0.f,0.f,0.f},
                  {0.f,0.f,0.f,0.f},{0.f,0.f,0.f,0.f}};
#pragma unroll
  for (int og = 0; og < 4; ++og) {
#pragma unroll
    for (int s = 0; s < 2; ++s) {
      const float* p = w + ((size_t)r * FF + og * 16 + row16) * FF + s * 32 + quad * 8;
      bf16x8 afr = cvt8(*(const f32x4*)p, *(const f32x4*)(p + 4));
      acc[og] = __builtin_amdgcn_mfma_f32_16x16x32_bf16(afr, bfr[s], acc[og], 0, 0, 0);
    }
  }

#pragma unroll
  for (int og = 0; og < 4; ++og)
#pragma unroll
    for (int j = 0; j < 4; ++j) {
      int o = og * 16 + quad * 4 + j;
      int m = m0 + row16;
      zt[((size_t)r * FF + o) * NN + m] = f2b(acc[og][j]);
    }
}

// ---------------------------------------------------------------------------
// Kernel 2: y[n][o] += sum_{m} A[r][n][m] * Zt[r][o][m]  (split-K atomics)
// grid = (64 row-tiles, 16 = r*2 + khalf), block 256 = 4 waves x 16 rows.
// Flat named-register software pipeline (NO structs -> no scratch risk):
//   A (HBM, fp32): prefetch depth 2 phases (phase = 64 k-floats)
//   B (Zt, L2-resident bf16): prefetch depth 1 phase
// No LDS, no barriers.

__device__ __forceinline__ void loadA(const float* __restrict__ p, int k,
                                      f32x4& l0, f32x4& h0, f32x4& l1, f32x4& h1) {
  l0 = *(const f32x4*)(p + k);
  h0 = *(const f32x4*)(p + k + 4);
  l1 = *(const f32x4*)(p + k + 32);
  h1 = *(const f32x4*)(p + k + 36);
}

__device__ __forceinline__ void loadB(const short* __restrict__ zb, int k,
                                      bf16x8& b0, bf16x8& b1, bf16x8& b2, bf16x8& b3,
                                      bf16x8& b4, bf16x8& b5, bf16x8& b6, bf16x8& b7) {
  b0 = *(const bf16x8*)(zb + (size_t)0 * 16 * NN + k);
  b1 = *(const bf16x8*)(zb + (size_t)1 * 16 * NN + k);
  b2 = *(const bf16x8*)(zb + (size_t)2 * 16 * NN + k);
  b3 = *(const bf16x8*)(zb + (size_t)3 * 16 * NN + k);
  b4 = *(const bf16x8*)(zb + (size_t)0 * 16 * NN + k + 32);
  b5 = *(const bf16x8*)(zb + (size_t)1 * 16 * NN + k + 32);
  b6 = *(const bf16x8*)(zb + (size_t)2 * 16 * NN + k + 32);
  b7 = *(const bf16x8*)(zb + (size_t)3 * 16 * NN + k + 32);
}

__device__ __forceinline__ void mfma4(bf16x8 a, bf16x8 b0, bf16x8 b1, bf16x8 b2, bf16x8 b3,
                                      f32x4* acc) {
  acc[0] = __builtin_amdgcn_mfma_f32_16x16x32_bf16(a, b0, acc[0], 0, 0, 0);
  acc[1] = __builtin_amdgcn_mfma_f32_16x16x32_bf16(a, b1, acc[1], 0, 0, 0);
  acc[2] = __builtin_amdgcn_mfma_f32_16x16x32_bf16(a, b2, acc[2], 0, 0, 0);
  acc[3] = __builtin_amdgcn_mfma_f32_16x16x32_bf16(a, b3, acc[3], 0, 0, 0);
}

__global__ __launch_bounds__(256, 2) void rgcn_main(const float* __restrict__ adj,
                                                    const short* __restrict__ zt,
                                                    float* __restrict__ out) {
  const int tid   = threadIdx.x;
  const int lane  = tid & 63;
  const int wv    = tid >> 6;
  const int row16 = lane & 15;
  const int quad  = lane >> 4;

  const int nt    = blockIdx.x;
  const int rk    = blockIdx.y;
  const int r     = rk >> 1;
  const int half  = rk & 1;
  const int n0    = nt * 64;
  const int row   = n0 + wv * 16 + row16;

  const float* aptr = adj + (size_t)r * NN * NN + (size_t)row * NN
                          + half * 2048 + quad * 8;
  const short* zb   = zt + (size_t)r * FF * NN + (size_t)row16 * NN
                         + half * 2048 + quad * 8;

  f32x4 acc[4] = {{0.f,0.f,0.f,0.f},{0.f,0.f,0.f,0.f},
                  {0.f,0.f,0.f,0.f},{0.f,0.f,0.f,0.f}};

  // Pipeline registers (all named scalars — no arrays, no structs).
  f32x4 A0l0, A0h0, A0l1, A0h1;   // A stage 0 (k0)
  f32x4 A1l0, A1h0, A1l1, A1h1;   // A stage 1 (k0+64)
  bf16x8 p0, p1, p2, p3, p4, p5, p6, p7;   // B stage 0
  bf16x8 q0, q1, q2, q3, q4, q5, q6, q7;   // B stage 1

  loadA(aptr, 0,  A0l0, A0h0, A0l1, A0h1);
  loadA(aptr, 64, A1l0, A1h0, A1l1, A1h1);
  loadB(zb, 0, p0, p1, p2, p3, p4, p5, p6, p7);

#pragma unroll 1
  for (int k0 = 0; k0 < 2048; k0 += 128) {
    // ---- phase A: compute k = k0 using A stage0 / B stage0 ----
    loadB(zb, (k0 + 64) & 2047, q0, q1, q2, q3, q4, q5, q6, q7);
    bf16x8 af0 = cvt8(A0l0, A0h0);
    bf16x8 af1 = cvt8(A0l1, A0h1);
    loadA(aptr, (k0 + 128) & 2047, A0l0, A0h0, A0l1, A0h1);
    mfma4(af0, p0, p1, p2, p3, acc);
    mfma4(af1, p4, p5, p6, p7, acc);

    // ---- phase B: compute k = k0+64 using A stage1 / B stage1 ----
    loadB(zb, (k0 + 128) & 2047, p0, p1, p2, p3, p4, p5, p6, p7);
    bf16x8 ag0 = cvt8(A1l0, A1h0);
    bf16x8 ag1 = cvt8(A1l1, A1h1);
    loadA(aptr, (k0 + 192) & 2047, A1l0, A1h0, A1l1, A1h1);
    mfma4(ag0, q0, q1, q2, q3, acc);
    mfma4(ag1, q4, q5, q6, q7, acc);
  }

  // Epilogue: C/D layout col = lane&15 (o within group), row = quad*4 + reg.
#pragma unroll
  for (int cg = 0; cg < 4; ++cg)
#pragma unroll
    for (int j = 0; j < 4; ++j) {
      int orow = n0 + wv * 16 + quad * 4 + j;
      int ocol = cg * 16 + row16;
      atomicAdd(out + (size_t)orow * FF + ocol, acc[cg][j]);
    }
}

// ---------------------------------------------------------------------------
extern "C" void kernel_launch(void* const* d_in, const int* in_sizes, int n_in,
                              void* d_out, int out_size, void* d_ws, size_t ws_size,
                              hipStream_t stream) {
  const float* adj = (const float*)d_in[0];   // [8, 4096, 4096] fp32
  const float* x   = (const float*)d_in[1];   // [4096, 64] fp32
  const float* w   = (const float*)d_in[2];   // [8, 64, 64] fp32
  float* out = (float*)d_out;                 // [4096, 64] fp32
  short* zt  = (short*)d_ws;                  // [8, 64, 4096] bf16 = 4 MiB

  zero_out<<<dim3(NN * FF / (4 * 256)), 256, 0, stream>>>((float4*)out);
  compute_zt<<<dim3(NN / 64, RR), 256, 0, stream>>>(x, w, zt);
  rgcn_main<<<dim3(NN / 64, RR * 2), 256, 0, stream>>>(adj, zt, out);
}

// Round 3
// 729.093 us; speedup vs baseline: 1.0398x; 1.0398x over previous
//
#include <hip/hip_runtime.h>
#include <hip/hip_bf16.h>

// Problem constants (reference: R=8, N=4096, IN_F=OUT_F=64)
#define RR 8
#define NN 4096
#define FF 64

typedef float f32x4 __attribute__((ext_vector_type(4)));
typedef short bf16x8 __attribute__((ext_vector_type(8)));

__device__ __forceinline__ short f2b(float f) {
  __hip_bfloat16 h = __float2bfloat16(f);
  return __builtin_bit_cast(short, h);
}

__device__ __forceinline__ bf16x8 cvt8(f32x4 lo, f32x4 hi) {
  bf16x8 r;
  r[0] = f2b(lo[0]); r[1] = f2b(lo[1]); r[2] = f2b(lo[2]); r[3] = f2b(lo[3]);
  r[4] = f2b(hi[0]); r[5] = f2b(hi[1]); r[6] = f2b(hi[2]); r[7] = f2b(hi[3]);
  return r;
}

// ---------------------------------------------------------------------------
// Kernel 1: Zt[r][o][m] = sum_i W[r][o][i] * x[m][i], stored bf16 in d_ws.
// (unchanged — verified correct in R1/R2)
__global__ __launch_bounds__(256) void compute_zt(const float* __restrict__ x,
                                                  const float* __restrict__ w,
                                                  short* __restrict__ zt) {
  const int tid   = threadIdx.x;
  const int lane  = tid & 63;
  const int wv    = tid >> 6;
  const int row16 = lane & 15;
  const int quad  = lane >> 4;
  const int r     = blockIdx.y;
  const int m0    = blockIdx.x * 64 + wv * 16;

  bf16x8 bfr[2];
#pragma unroll
  for (int s = 0; s < 2; ++s) {
    const float* p = x + (size_t)(m0 + row16) * FF + s * 32 + quad * 8;
    bfr[s] = cvt8(*(const f32x4*)p, *(const f32x4*)(p + 4));
  }

  f32x4 acc[4] = {{0.f,0.f,0.f,0.f},{0.f,0.f,0.f,0.f},
                  {0.f,0.f,0.f,0.f},{0.f,0.f,0.f,0.f}};
#pragma unroll
  for (int og = 0; og < 4; ++og) {
#pragma unroll
    for (int s = 0; s < 2; ++s) {
      const float* p = w + ((size_t)r * FF + og * 16 + row16) * FF + s * 32 + quad * 8;
      bf16x8 afr = cvt8(*(const f32x4*)p, *(const f32x4*)(p + 4));
      acc[og] = __builtin_amdgcn_mfma_f32_16x16x32_bf16(afr, bfr[s], acc[og], 0, 0, 0);
    }
  }

#pragma unroll
  for (int og = 0; og < 4; ++og)
#pragma unroll
    for (int j = 0; j < 4; ++j) {
      int o = og * 16 + quad * 4 + j;
      int m = m0 + row16;
      zt[((size_t)r * FF + o) * NN + m] = f2b(acc[og][j]);
    }
}

// ---------------------------------------------------------------------------
// Kernel 2: partial[rk][n][o] = sum_{m in half} A[r][n][m] * Zt[r][o][m]
// grid = (64 row-tiles, 16 = r*2 + khalf), block 256 = 4 waves x 16 rows.
// A is staged block-cooperatively: every global load instruction covers a
// CONTIGUOUS 512B run of one adjacency row (lane-consecutive addresses) so
// HBM sees long per-row bursts instead of 65K interleaved 256B streams.
// fp32 -> bf16 convert in regs, double-buffered bf16 LDS, MFMA from LDS.
// No atomics: partials written plain, reduced by kernel 3.

#define BK    128                 // k-floats per stage
#define NSTG  16                  // 2048 / BK
#define LROW  136                 // LDS row stride in shorts (128 + 8 pad)

__device__ __forceinline__ void issueA(const float* __restrict__ abase,
                                       int trow, int tcol, int s, f32x4* av) {
#pragma unroll
  for (int i = 0; i < 8; ++i)
    av[i] = *(const f32x4*)(abase + (size_t)(i * 8 + trow) * NN + s * BK + tcol);
}

__device__ __forceinline__ void writeA(short* __restrict__ buf,
                                       int trow, int tcol, const f32x4* av) {
#pragma unroll
  for (int i = 0; i < 8; ++i) {
    short4 wv4;
    wv4.x = f2b(av[i][0]); wv4.y = f2b(av[i][1]);
    wv4.z = f2b(av[i][2]); wv4.w = f2b(av[i][3]);
    *(short4*)(buf + (i * 8 + trow) * LROW + tcol) = wv4;
  }
}

__device__ __forceinline__ void loadB4(const short* __restrict__ zb, int k, bf16x8* b) {
#pragma unroll
  for (int cg = 0; cg < 4; ++cg)
    b[cg] = *(const bf16x8*)(zb + (size_t)cg * 16 * NN + k);
}

__device__ __forceinline__ void mfma4(bf16x8 a, const bf16x8* b, f32x4* acc) {
  acc[0] = __builtin_amdgcn_mfma_f32_16x16x32_bf16(a, b[0], acc[0], 0, 0, 0);
  acc[1] = __builtin_amdgcn_mfma_f32_16x16x32_bf16(a, b[1], acc[1], 0, 0, 0);
  acc[2] = __builtin_amdgcn_mfma_f32_16x16x32_bf16(a, b[2], acc[2], 0, 0, 0);
  acc[3] = __builtin_amdgcn_mfma_f32_16x16x32_bf16(a, b[3], acc[3], 0, 0, 0);
}

__global__ __launch_bounds__(256, 3) void rgcn_main(const float* __restrict__ adj,
                                                    const short* __restrict__ zt,
                                                    float* __restrict__ partial) {
  __shared__ short lds[2][64 * LROW];   // 2 x 17 KiB

  const int tid   = threadIdx.x;
  const int lane  = tid & 63;
  const int wv    = tid >> 6;
  const int row16 = lane & 15;
  const int quad  = lane >> 4;

  const int nt   = blockIdx.x;
  const int rk   = blockIdx.y;
  const int r    = rk >> 1;
  const int half = rk & 1;
  const int n0   = nt * 64;

  // Cooperative A-staging mapping: thread t, instr i reads
  // row = i*8 + (t>>5), floats [ (t&31)*4 , +4 ) of the 128-float stage chunk.
  // => each wave-instruction = 2 rows x 512B fully contiguous, lane-ordered.
  const int trow = tid >> 5;          // 0..7
  const int tcol = (tid & 31) * 4;    // 0..124

  const float* abase = adj + (size_t)r * NN * NN + (size_t)n0 * NN + half * 2048;
  const short* zb    = zt + (size_t)r * FF * NN + (size_t)row16 * NN
                          + half * 2048 + quad * 8;

  f32x4 acc[4] = {{0.f,0.f,0.f,0.f},{0.f,0.f,0.f,0.f},
                  {0.f,0.f,0.f,0.f},{0.f,0.f,0.f,0.f}};
  f32x4 av[8];

  // Prologue: stage 0 -> LDS buf0; stage 1 loads in flight.
  issueA(abase, trow, tcol, 0, av);
  writeA(&lds[0][0], trow, tcol, av);
  issueA(abase, trow, tcol, 1, av);
  __syncthreads();

#pragma unroll 1
  for (int s = 0; s < NSTG; ++s) {
    const short* fb = &lds[s & 1][(wv * 16 + row16) * LROW + quad * 8];

    bf16x8 b0[4], b1[4];
    loadB4(zb, s * BK,      b0);
    loadB4(zb, s * BK + 32, b1);

    bf16x8 a0 = *(const bf16x8*)(fb + 0);
    mfma4(a0, b0, acc);
    loadB4(zb, s * BK + 64, b0);
    bf16x8 a1 = *(const bf16x8*)(fb + 32);
    mfma4(a1, b1, acc);
    loadB4(zb, s * BK + 96, b1);
    bf16x8 a2 = *(const bf16x8*)(fb + 64);
    mfma4(a2, b0, acc);
    bf16x8 a3 = *(const bf16x8*)(fb + 96);
    mfma4(a3, b1, acc);

    if (s < NSTG - 1) {
      writeA(&lds[(s + 1) & 1][0], trow, tcol, av);   // stage s+1 -> other buf
      if (s < NSTG - 2) issueA(abase, trow, tcol, s + 2, av);
      __syncthreads();
    }
  }

  // Epilogue: plain stores of this block's partial tile.
  float* pb = partial + ((size_t)rk * NN + n0) * FF;
#pragma unroll
  for (int cg = 0; cg < 4; ++cg)
#pragma unroll
    for (int j = 0; j < 4; ++j)
      pb[(size_t)(wv * 16 + quad * 4 + j) * FF + cg * 16 + row16] = acc[cg][j];
}

// ---------------------------------------------------------------------------
// Kernel 3: out[n][o] = sum_{rk=0..15} partial[rk][n][o]   (f32x4 vectorized)
__global__ __launch_bounds__(256) void reduce_partials(const f32x4* __restrict__ p,
                                                       f32x4* __restrict__ out) {
  const int idx = blockIdx.x * 256 + threadIdx.x;   // 65536 f32x4 elements
  f32x4 s = {0.f, 0.f, 0.f, 0.f};
#pragma unroll
  for (int rk = 0; rk < 16; ++rk)
    s += p[(size_t)rk * (NN * FF / 4) + idx];
  out[idx] = s;
}

// ---------------------------------------------------------------------------
extern "C" void kernel_launch(void* const* d_in, const int* in_sizes, int n_in,
                              void* d_out, int out_size, void* d_ws, size_t ws_size,
                              hipStream_t stream) {
  const float* adj = (const float*)d_in[0];   // [8, 4096, 4096] fp32
  const float* x   = (const float*)d_in[1];   // [4096, 64] fp32
  const float* w   = (const float*)d_in[2];   // [8, 64, 64] fp32
  float* out = (float*)d_out;                 // [4096, 64] fp32

  short* zt      = (short*)d_ws;                            // 4 MiB
  float* partial = (float*)((char*)d_ws + (16u << 20));     // 16 MiB @ +16 MiB

  compute_zt<<<dim3(NN / 64, RR), 256, 0, stream>>>(x, w, zt);
  rgcn_main<<<dim3(NN / 64, RR * 2), 256, 0, stream>>>(adj, zt, partial);
  reduce_partials<<<dim3(NN * FF / 4 / 256), 256, 0, stream>>>(
      (const f32x4*)partial, (f32x4*)out);
}